// Round 5
// baseline (7219.300 us; speedup 1.0000x reference)
//
#include <hip/hip_runtime.h>
#include <math.h>

// Semi-relaxed Sinkhorn-Knopp, MI355X. B=16, n=4096, k=1024, K=1025.
// R5: one launch per iteration, NO global sync, NO spinning. Blocks publish
// column partials with agent-scope write-through stores; a per-batch ticket
// (acq-rel) elects the LAST-arriving block of each batch as that batch's
// reducer, which immediately reduces 64x1024 partials -> b-update, err, e2,
// flag — overlapped with other batches' Q-passes. Next kernel reads only the
// 4KB bnew (fresh via kernel-boundary acquire). Iter 0 fuses prep (Q from
// logits, bf16). Plan recomputes fp32 Q from logits.

namespace {
constexpr int   Bn      = 16;
constexpr int   Kc      = 1024;    // k
constexpr int   KK      = 1025;    // K = k+1 (dustbin)
constexpr int   BSTR    = 1028;    // padded b stride
constexpr int   ROWS    = 65536;   // B*n
constexpr int   NBLK    = 1024;    // iter blocks, 64 rows each (64 per batch)
constexpr float INV_EPS = 10.0f;
constexpr float PA      = 1.0f / 4096.0f;
constexpr float PB_LOW  = (float)(0.5 / 1024.0);
constexpr float PB_DUST = 0.5f;
constexpr float FI_F    = (float)(1.0 / 1.1); // GAMMA/(GAMMA+EPS)
constexpr float STOP    = 1e-6f;
constexpr int   NITER   = 100;
} // namespace

typedef __attribute__((ext_vector_type(8))) unsigned short ushort8;

#define LOADX(p)    __hip_atomic_load((p), __ATOMIC_RELAXED, __HIP_MEMORY_SCOPE_AGENT)
#define STOREX(p,v) __hip_atomic_store((p), (v), __ATOMIC_RELAXED, __HIP_MEMORY_SCOPE_AGENT)

__device__ __forceinline__ float wredsum(float v) {
#pragma unroll
  for (int m = 32; m >= 1; m >>= 1) v += __shfl_xor(v, m, 64);
  return v;
}
__device__ __forceinline__ float wredmax(float v) {
#pragma unroll
  for (int m = 32; m >= 1; m >>= 1) v = fmaxf(v, __shfl_xor(v, m, 64));
  return v;
}
__device__ __forceinline__ unsigned short f2bf(float x) {
  unsigned int u = __float_as_uint(x);
  return (unsigned short)((u + 0x7FFFu + ((u >> 16) & 1u)) >> 16);  // RNE
}
__device__ __forceinline__ float bf2f(unsigned short h) {
  return __uint_as_float(((unsigned int)h) << 16);
}

// ---------------- init ----------------
__global__ void k_init(float* __restrict__ bnew, float* __restrict__ e2acc,
                       int* __restrict__ cntB, int* __restrict__ cnt2,
                       int* __restrict__ flag) {
  int tid = blockIdx.x * blockDim.x + threadIdx.x;
  int stride = gridDim.x * blockDim.x;
  for (int i = tid; i < Bn * BSTR; i += stride) {
    int j = i % BSTR;
    bnew[i] = (j < KK) ? (float)(1.0 / 1025.0) : 0.0f;
  }
  for (int i = tid; i < NITER; i += stride) { e2acc[i] = 0.0f; cnt2[i] = 0; }
  for (int i = tid; i < NITER * Bn; i += stride) cntB[i] = 0;
  if (tid == 0) *flag = 1;
}

// ---------------- fused iteration + batch-local reducer ----------------
template <bool FIRST>
__global__ __launch_bounds__(256) void k_iter(
    const float* __restrict__ x, unsigned short* __restrict__ Qb,
    float* __restrict__ bnew, float* __restrict__ avec,
    float* __restrict__ part, float* __restrict__ sumaPart,
    float* __restrict__ e2acc, int* __restrict__ cntB, int* __restrict__ cnt2,
    int* __restrict__ flag, int it) {
  __shared__ float cpart[4][1024];
  __shared__ float sred[4];
  __shared__ int shi;
  const int tid = threadIdx.x, wid = tid >> 6, lane = tid & 63;
  if (tid == 0) shi = *flag;
  __syncthreads();
  if (shi == 0) return;

  const int blk = blockIdx.x;
  const int baseRow = blk * 64;
  const int batch = blk >> 6;

  const float4* bp = (const float4*)(bnew + batch * BSTR);
  float4 bb[4];
#pragma unroll
  for (int s = 0; s < 4; ++s) bb[s] = bp[lane * 4 + s];
  const float bdust = bnew[batch * BSTR + 1024];

  float acc[16];
#pragma unroll
  for (int e = 0; e < 16; ++e) acc[e] = 0.0f;
  float sal = 0.0f;

  const int rowBase = baseRow + wid * 16;
#pragma unroll 4
  for (int r = 0; r < 16; ++r) {
    float q[16];
    if constexpr (FIRST) {
      const float4* xp = (const float4*)(x + ((size_t)(rowBase + r) << 10));
      float4 v[4];
#pragma unroll
      for (int s = 0; s < 4; ++s) v[s] = xp[lane * 4 + s];
      float m = -1e30f;
#pragma unroll
      for (int s = 0; s < 4; ++s)
        m = fmaxf(m, fmaxf(fmaxf(v[s].x, v[s].y), fmaxf(v[s].z, v[s].w)));
      m = wredmax(m);
      float su = 0.0f;
#pragma unroll
      for (int s = 0; s < 4; ++s)
        su += expf(v[s].x - m) + expf(v[s].y - m) + expf(v[s].z - m) + expf(v[s].w - m);
      su = wredsum(su);
      const float lse = m + logf(su);
      ushort8 qa, qb2;
#pragma unroll
      for (int s = 0; s < 4; ++s) {
        const unsigned short u0 = f2bf(expf((v[s].x - lse) * INV_EPS));
        const unsigned short u1 = f2bf(expf((v[s].y - lse) * INV_EPS));
        const unsigned short u2 = f2bf(expf((v[s].z - lse) * INV_EPS));
        const unsigned short u3 = f2bf(expf((v[s].w - lse) * INV_EPS));
        if (s < 2) { qa[s*4+0]=u0; qa[s*4+1]=u1; qa[s*4+2]=u2; qa[s*4+3]=u3; }
        else { qb2[(s-2)*4+0]=u0; qb2[(s-2)*4+1]=u1; qb2[(s-2)*4+2]=u2; qb2[(s-2)*4+3]=u3; }
        q[s*4+0]=bf2f(u0); q[s*4+1]=bf2f(u1); q[s*4+2]=bf2f(u2); q[s*4+3]=bf2f(u3);
      }
      ushort8* qp = (ushort8*)(Qb + ((size_t)(rowBase + r) << 10));
      qp[lane * 2] = qa; qp[lane * 2 + 1] = qb2;
    } else {
      const ushort8* qp = (const ushort8*)(Qb + ((size_t)(rowBase + r) << 10));
      const ushort8 qa = qp[lane * 2], qb2 = qp[lane * 2 + 1];
#pragma unroll
      for (int e = 0; e < 8; ++e) { q[e] = bf2f(qa[e]); q[8 + e] = bf2f(qb2[e]); }
    }

    float p = 0.0f;
#pragma unroll
    for (int s = 0; s < 4; ++s)
      p += q[s * 4 + 0] * bb[s].x + q[s * 4 + 1] * bb[s].y +
           q[s * 4 + 2] * bb[s].z + q[s * 4 + 3] * bb[s].w;

    const float inner = wredsum(p) + bdust;       // dustbin Q == 1
    const float a = PA / inner;                   // broadcast to all lanes
    if (lane == 0) { avec[rowBase + r] = a; sal += a; }
#pragma unroll
    for (int e = 0; e < 16; ++e) acc[e] += q[e] * a;
  }
  if (lane == 0) sred[wid] = sal;

  float4* cp = (float4*)&cpart[wid][lane * 16];
#pragma unroll
  for (int s = 0; s < 4; ++s)
    cp[s] = make_float4(acc[s * 4 + 0], acc[s * 4 + 1], acc[s * 4 + 2], acc[s * 4 + 3]);
  __syncthreads();

  {
    const int j = tid * 4;
    float* pb = part + ((size_t)blk << 10) + j;
#pragma unroll
    for (int e = 0; e < 4; ++e) {
      const float v = cpart[0][j + e] + cpart[1][j + e] + cpart[2][j + e] + cpart[3][j + e];
      STOREX(pb + e, v);
    }
    if (tid == 0)
      STOREX(&sumaPart[blk], sred[0] + sred[1] + sred[2] + sred[3]);
  }
  __syncthreads();   // vmcnt drained for all waves' part stores
  if (tid == 0)
    shi = __hip_atomic_fetch_add(&cntB[it * Bn + batch], 1,
                                 __ATOMIC_ACQ_REL, __HIP_MEMORY_SCOPE_AGENT);
  __syncthreads();
  if (shi != 63) return;            // not the last block of this batch

  // ------- batch reducer: this block arrived LAST for its batch -------
  const float* pbase = part + (((size_t)batch * 64) << 10);
  const int c = tid * 4;
  float s0 = 0.0f, s1 = 0.0f, s2 = 0.0f, s3 = 0.0f;
#pragma unroll 8
  for (int sb = 0; sb < 64; ++sb) {
    const unsigned long long* pp =
        (const unsigned long long*)(pbase + (((size_t)sb) << 10) + c);
    const unsigned long long u0 = LOADX(pp), u1 = LOADX(pp + 1);
    s0 += __uint_as_float((unsigned)u0);  s1 += __uint_as_float((unsigned)(u0 >> 32));
    s2 += __uint_as_float((unsigned)u1);  s3 += __uint_as_float((unsigned)(u1 >> 32));
  }
  float e2 = 0.0f;
  float* bslot = bnew + batch * BSTR + c;
  {
    const float bo0 = LOADX(bslot + 0), bo1 = LOADX(bslot + 1);
    const float bo2 = LOADX(bslot + 2), bo3 = LOADX(bslot + 3);
    const float n0 = exp2f(FI_F * log2f(PB_LOW / s0));
    const float n1 = exp2f(FI_F * log2f(PB_LOW / s1));
    const float n2 = exp2f(FI_F * log2f(PB_LOW / s2));
    const float n3 = exp2f(FI_F * log2f(PB_LOW / s3));
    STOREX(bslot + 0, n0); STOREX(bslot + 1, n1);
    STOREX(bslot + 2, n2); STOREX(bslot + 3, n3);
    e2 = (n0-bo0)*(n0-bo0) + (n1-bo1)*(n1-bo1) +
         (n2-bo2)*(n2-bo2) + (n3-bo3)*(n3-bo3);
  }
  if (wid == 0) {                    // wave 0: dustbin column
    float sa = LOADX(&sumaPart[batch * 64 + lane]);
    sa = wredsum(sa);
    if (lane == 0) {
      float* ds = bnew + batch * BSTR + 1024;
      const float bo = LOADX(ds);
      const float bn = PB_DUST / sa;
      STOREX(ds, bn);
      e2 += (bn - bo) * (bn - bo);
    }
  }
  const float e2w = wredsum(e2);
  if (lane == 0) sred[wid] = e2w;
  __syncthreads();
  if (tid == 0) {
    const float e2b = sred[0] + sred[1] + sred[2] + sred[3];
    __hip_atomic_fetch_add(&e2acc[it], e2b, __ATOMIC_RELAXED, __HIP_MEMORY_SCOPE_AGENT);
    const int t2 = __hip_atomic_fetch_add(&cnt2[it], 1,
                                          __ATOMIC_ACQ_REL, __HIP_MEMORY_SCOPE_AGENT);
    if (t2 == Bn - 1) {
      const float err = sqrtf(LOADX(&e2acc[it]));
      if (!(err > STOP)) STOREX(flag, 0);   // NaN also stops, like jnp cond
    }
  }
}

// ---------------- plan: recompute fp32 Q from logits; out = a*Q*b*n -------
__global__ __launch_bounds__(256) void k_plan(const float* __restrict__ x,
                                              float* __restrict__ out,
                                              const float* __restrict__ avec,
                                              const float* __restrict__ bvec) {
  const int wid = threadIdx.x >> 6, lane = threadIdx.x & 63;
  const int row = blockIdx.x * 4 + wid;
  const int batch = row >> 12;
  const float4* xp = (const float4*)(x + ((size_t)row << 10));
  float4 v[4];
#pragma unroll
  for (int s = 0; s < 4; ++s) v[s] = xp[lane * 4 + s];

  float m = -1e30f;
#pragma unroll
  for (int s = 0; s < 4; ++s)
    m = fmaxf(m, fmaxf(fmaxf(v[s].x, v[s].y), fmaxf(v[s].z, v[s].w)));
  m = wredmax(m);
  float sum = 0.0f;
#pragma unroll
  for (int s = 0; s < 4; ++s)
    sum += expf(v[s].x - m) + expf(v[s].y - m) + expf(v[s].z - m) + expf(v[s].w - m);
  sum = wredsum(sum);
  const float lse = m + logf(sum);

  const float sc = avec[row] * 4096.0f;
  const float4* bp = (const float4*)(bvec + batch * BSTR);
  float4* op = (float4*)(out + ((size_t)row << 10));
#pragma unroll
  for (int s = 0; s < 4; ++s) {
    const float4 b = bp[lane * 4 + s];
    float4 o;
    o.x = expf((v[s].x - lse) * INV_EPS) * sc * b.x;
    o.y = expf((v[s].y - lse) * INV_EPS) * sc * b.y;
    o.z = expf((v[s].z - lse) * INV_EPS) * sc * b.z;
    o.w = expf((v[s].w - lse) * INV_EPS) * sc * b.w;
    op[lane * 4 + s] = o;
  }
}

extern "C" void kernel_launch(void* const* d_in, const int* in_sizes, int n_in,
                              void* d_out, int out_size, void* d_ws, size_t ws_size,
                              hipStream_t stream) {
  const float* logits = (const float*)d_in[0];
  unsigned short* Qb = (unsigned short*)d_out;   // bf16 Q in first half of d_out
  float* ws = (float*)d_ws;
  float* bnew     = ws;                          // 16*1028
  float* avec     = bnew + Bn * BSTR;            // 65536
  float* part     = avec + ROWS;                 // 1024*1024
  float* sumaPart = part + (size_t)NBLK * Kc;    // 1024
  float* e2acc    = sumaPart + NBLK;             // NITER
  int*   cntB     = (int*)(e2acc + NITER);       // NITER*16
  int*   cnt2     = cntB + NITER * Bn;           // NITER
  int*   flag     = cnt2 + NITER;                // 1

  k_init<<<64, 256, 0, stream>>>(bnew, e2acc, cntB, cnt2, flag);
  k_iter<true><<<NBLK, 256, 0, stream>>>(logits, Qb, bnew, avec, part, sumaPart,
                                         e2acc, cntB, cnt2, flag, 0);
  for (int it = 1; it < NITER; ++it)
    k_iter<false><<<NBLK, 256, 0, stream>>>(logits, Qb, bnew, avec, part, sumaPart,
                                            e2acc, cntB, cnt2, flag, it);
  k_plan<<<ROWS / 4, 256, 0, stream>>>(logits, (float*)d_out, avec, bnew);
}

// Round 6
// 4148.269 us; speedup vs baseline: 1.7403x; 1.7403x over previous
//
#include <hip/hip_runtime.h>
#include <math.h>

// Semi-relaxed Sinkhorn-Knopp, MI355X. B=16, n=4096, k=1024, K=1025.
// R6: fin-at-head. Launch t's blocks 0..63 reduce iteration t-1's column
// partials (plain loads; kernel boundary gives coherence), update b (STOREX),
// err, flag, then release a monotonic `ready` word. All blocks wait on
// `ready`, LOADX the fresh b, then run the atomic-free Q pass (R3's proven
// hot loop: plain part/avec stores). One launch per iteration. Deadlock-safe:
// fin blocks wait for nobody; __launch_bounds__(256,4) makes all 1024 blocks
// co-resident. Iter 0 fuses prep (Q bf16 + lse cached). Plan uses cached lse.

namespace {
constexpr int   Bn      = 16;
constexpr int   Kc      = 1024;    // k
constexpr int   KK      = 1025;    // K = k+1 (dustbin)
constexpr int   BSTR    = 1028;    // padded b stride
constexpr int   ROWS    = 65536;   // B*n
constexpr int   NBLK    = 1024;    // iter blocks, 64 rows each (64 per batch)
constexpr float PA      = 1.0f / 4096.0f;
constexpr float PB_LOW  = (float)(0.5 / 1024.0);
constexpr float PB_DUST = 0.5f;
constexpr float FI_F    = (float)(1.0 / 1.1); // GAMMA/(GAMMA+EPS)
constexpr float STOP    = 1e-6f;
constexpr int   NITER   = 100;
constexpr float LOG2E   = 1.44269504088896340736f;
constexpr float ILOG2E  = 0.69314718055994530942f;
constexpr float TLOG2E  = 14.4269504088896340736f;  // 10*log2(e)
} // namespace

typedef __attribute__((ext_vector_type(8))) unsigned short ushort8;

#define LOADX(p)    __hip_atomic_load((p), __ATOMIC_RELAXED, __HIP_MEMORY_SCOPE_AGENT)
#define STOREX(p,v) __hip_atomic_store((p), (v), __ATOMIC_RELAXED, __HIP_MEMORY_SCOPE_AGENT)

__device__ __forceinline__ float wredsum(float v) {
#pragma unroll
  for (int m = 32; m >= 1; m >>= 1) v += __shfl_xor(v, m, 64);
  return v;
}
__device__ __forceinline__ float wredmax(float v) {
#pragma unroll
  for (int m = 32; m >= 1; m >>= 1) v = fmaxf(v, __shfl_xor(v, m, 64));
  return v;
}
__device__ __forceinline__ unsigned short f2bf(float x) {
  unsigned int u = __float_as_uint(x);
  return (unsigned short)((u + 0x7FFFu + ((u >> 16) & 1u)) >> 16);  // RNE
}
__device__ __forceinline__ float bf2f(unsigned short h) {
  return __uint_as_float(((unsigned int)h) << 16);
}

// ---------------- init ----------------
__global__ void k_init(float* __restrict__ bnew, float* __restrict__ e2acc,
                       int* __restrict__ cnt2, int* __restrict__ flag,
                       int* __restrict__ ready) {
  int tid = blockIdx.x * blockDim.x + threadIdx.x;
  int stride = gridDim.x * blockDim.x;
  for (int i = tid; i < Bn * BSTR; i += stride) {
    int j = i % BSTR;
    bnew[i] = (j < KK) ? (float)(1.0 / 1025.0) : 0.0f;
  }
  for (int i = tid; i <= NITER; i += stride) { e2acc[i] = 0.0f; cnt2[i] = 0; }
  if (tid == 0) { *flag = 1; *ready = 0; }
}

// ------- fin for the PREVIOUS iteration: 64 blocks, 1 thread per column ----
__device__ __forceinline__ void fin_block(
    const int blk, const int tid, const int slot,
    const float* __restrict__ part, const float* __restrict__ sumaPart,
    float* __restrict__ bnew, float* __restrict__ e2acc,
    int* __restrict__ cnt2, int* __restrict__ flag, int* __restrict__ ready,
    float* sred) {
  const int wid = tid >> 6, lane = tid & 63;
  const int batch = blk >> 2;
  const int col = ((blk & 3) << 8) + tid;
  const int f = LOADX(flag);
  float e2 = 0.0f;
  if (f != 0) {
    const float* pbase = part + ((size_t)batch << 16) + col;  // batch*64*1024
    float s = 0.0f;
#pragma unroll 8
    for (int sb = 0; sb < 64; ++sb) s += pbase[(size_t)sb << 10];
    float* bslot = bnew + batch * BSTR + col;
    const float bo = *bslot;                     // prev launch: plain is fresh
    const float bn = exp2f(FI_F * log2f(PB_LOW / s));
    STOREX(bslot, bn);
    e2 = (bn - bo) * (bn - bo);
    if (((blk & 3) == 0) && wid == 0) {          // dustbin column
      float sa = sumaPart[(batch << 6) + lane];
      sa = wredsum(sa);
      if (lane == 0) {
        float* ds = bnew + batch * BSTR + 1024;
        const float bo2 = *ds;
        const float bn2 = PB_DUST / sa;
        STOREX(ds, bn2);
        e2 += (bn2 - bo2) * (bn2 - bo2);
      }
    }
  }
  const float ew = wredsum(e2);
  if (lane == 0) sred[wid] = ew;
  __syncthreads();
  if (tid == 0) {
    if (f != 0)
      __hip_atomic_fetch_add(&e2acc[slot], sred[0] + sred[1] + sred[2] + sred[3],
                             __ATOMIC_RELAXED, __HIP_MEMORY_SCOPE_AGENT);
    const int t2 = __hip_atomic_fetch_add(&cnt2[slot], 1,
                                          __ATOMIC_ACQ_REL, __HIP_MEMORY_SCOPE_AGENT);
    if (t2 == 63) {
      if (f != 0) {
        const float err = sqrtf(LOADX(&e2acc[slot]));
        if (!(err > STOP)) STOREX(flag, 0);      // NaN also stops, like jnp
      }
      __hip_atomic_store(ready, slot, __ATOMIC_RELEASE, __HIP_MEMORY_SCOPE_AGENT);
    }
  }
}

// ---------------- iteration: [fin prev] -> wait -> Q pass ----------------
template <bool FIRST>
__global__ __launch_bounds__(256, 4) void k_iter(
    const float* __restrict__ x, unsigned short* __restrict__ Qb,
    float* __restrict__ lsev, float* __restrict__ bnew,
    float* __restrict__ avec, float* __restrict__ part,
    float* __restrict__ sumaPart, float* __restrict__ e2acc,
    int* __restrict__ cnt2, int* __restrict__ flag, int* __restrict__ ready,
    const int slot) {
  __shared__ float cpart[4][1024];
  __shared__ float sred[4];
  __shared__ int sflag;
  const int tid = threadIdx.x, wid = tid >> 6, lane = tid & 63;
  const int blk = blockIdx.x;

  if constexpr (!FIRST) {
    if (blk < 64)
      fin_block(blk, tid, slot, part, sumaPart, bnew, e2acc, cnt2, flag, ready, sred);
  }
  if (tid == 0) {
    if constexpr (!FIRST) {
      while (__hip_atomic_load(ready, __ATOMIC_RELAXED, __HIP_MEMORY_SCOPE_AGENT) < slot)
        __builtin_amdgcn_s_sleep(1);
      (void)__hip_atomic_load(ready, __ATOMIC_ACQUIRE, __HIP_MEMORY_SCOPE_AGENT);
    }
    sflag = LOADX(flag);
  }
  __syncthreads();
  if (sflag == 0) return;

  const int batch = blk >> 6;
  // b for this batch: coherence-point loads (written in-kernel by fin)
  float4 bb[4];
  const unsigned long long* bq =
      (const unsigned long long*)(bnew + batch * BSTR) + (lane << 3);
#pragma unroll
  for (int s = 0; s < 4; ++s) {
    const unsigned long long u0 = LOADX(bq + (s << 1));
    const unsigned long long u1 = LOADX(bq + (s << 1) + 1);
    bb[s].x = __uint_as_float((unsigned)u0);
    bb[s].y = __uint_as_float((unsigned)(u0 >> 32));
    bb[s].z = __uint_as_float((unsigned)u1);
    bb[s].w = __uint_as_float((unsigned)(u1 >> 32));
  }
  const float bdust = LOADX(bnew + batch * BSTR + 1024);

  float acc[16];
#pragma unroll
  for (int e = 0; e < 16; ++e) acc[e] = 0.0f;
  float sal = 0.0f;

  const int rowBase = (blk << 6) + (wid << 4);
#pragma unroll 4
  for (int r = 0; r < 16; ++r) {
    float q[16];
    if constexpr (FIRST) {
      const float4* xp = (const float4*)(x + ((size_t)(rowBase + r) << 10));
      float4 v[4];
#pragma unroll
      for (int s = 0; s < 4; ++s) v[s] = xp[(lane << 2) + s];
      float m = -1e30f;
#pragma unroll
      for (int s = 0; s < 4; ++s)
        m = fmaxf(m, fmaxf(fmaxf(v[s].x, v[s].y), fmaxf(v[s].z, v[s].w)));
      m = wredmax(m);
      float su = 0.0f;
#pragma unroll
      for (int s = 0; s < 4; ++s)
        su += exp2f((v[s].x - m) * LOG2E) + exp2f((v[s].y - m) * LOG2E) +
              exp2f((v[s].z - m) * LOG2E) + exp2f((v[s].w - m) * LOG2E);
      su = wredsum(su);
      const float lse = m + log2f(su) * ILOG2E;
      if (lane == 0) lsev[rowBase + r] = lse;
      ushort8 qa, qb2;
#pragma unroll
      for (int s = 0; s < 4; ++s) {
        const unsigned short u0 = f2bf(exp2f((v[s].x - lse) * TLOG2E));
        const unsigned short u1 = f2bf(exp2f((v[s].y - lse) * TLOG2E));
        const unsigned short u2 = f2bf(exp2f((v[s].z - lse) * TLOG2E));
        const unsigned short u3 = f2bf(exp2f((v[s].w - lse) * TLOG2E));
        if (s < 2) { qa[s*4+0]=u0; qa[s*4+1]=u1; qa[s*4+2]=u2; qa[s*4+3]=u3; }
        else { qb2[(s-2)*4+0]=u0; qb2[(s-2)*4+1]=u1; qb2[(s-2)*4+2]=u2; qb2[(s-2)*4+3]=u3; }
        q[s*4+0]=bf2f(u0); q[s*4+1]=bf2f(u1); q[s*4+2]=bf2f(u2); q[s*4+3]=bf2f(u3);
      }
      ushort8* qp = (ushort8*)(Qb + ((size_t)(rowBase + r) << 10));
      qp[lane * 2] = qa; qp[lane * 2 + 1] = qb2;
    } else {
      const ushort8* qp = (const ushort8*)(Qb + ((size_t)(rowBase + r) << 10));
      const ushort8 qa = qp[lane * 2], qb2 = qp[lane * 2 + 1];
#pragma unroll
      for (int e = 0; e < 8; ++e) { q[e] = bf2f(qa[e]); q[8 + e] = bf2f(qb2[e]); }
    }

    float p = 0.0f;
#pragma unroll
    for (int s = 0; s < 4; ++s)
      p += q[s * 4 + 0] * bb[s].x + q[s * 4 + 1] * bb[s].y +
           q[s * 4 + 2] * bb[s].z + q[s * 4 + 3] * bb[s].w;

    const float inner = wredsum(p) + bdust;       // dustbin Q == 1
    const float a = PA / inner;                   // broadcast to all lanes
    if (lane == 0) { avec[rowBase + r] = a; sal += a; }
#pragma unroll
    for (int e = 0; e < 16; ++e) acc[e] += q[e] * a;
  }
  if (lane == 0) sred[wid] = sal;

  float4* cp = (float4*)&cpart[wid][lane << 4];
#pragma unroll
  for (int s = 0; s < 4; ++s)
    cp[s] = make_float4(acc[s * 4 + 0], acc[s * 4 + 1], acc[s * 4 + 2], acc[s * 4 + 3]);
  __syncthreads();

  // plain stores: consumed only by the NEXT launch (kernel-boundary coherence)
  const int j = tid << 2;
  float4 o;
  o.x = cpart[0][j+0] + cpart[1][j+0] + cpart[2][j+0] + cpart[3][j+0];
  o.y = cpart[0][j+1] + cpart[1][j+1] + cpart[2][j+1] + cpart[3][j+1];
  o.z = cpart[0][j+2] + cpart[1][j+2] + cpart[2][j+2] + cpart[3][j+2];
  o.w = cpart[0][j+3] + cpart[1][j+3] + cpart[2][j+3] + cpart[3][j+3];
  ((float4*)(part + ((size_t)blk << 10)))[tid] = o;
  if (tid == 0) sumaPart[blk] = sred[0] + sred[1] + sred[2] + sred[3];
}

// ---------------- tail fin (iteration 99) ----------------
__global__ __launch_bounds__(256) void k_fin_tail(
    const float* __restrict__ part, const float* __restrict__ sumaPart,
    float* __restrict__ bnew, float* __restrict__ e2acc,
    int* __restrict__ cnt2, int* __restrict__ flag, int* __restrict__ ready) {
  __shared__ float sred[4];
  fin_block(blockIdx.x, threadIdx.x, NITER, part, sumaPart, bnew, e2acc, cnt2,
            flag, ready, sred);
}

// ---------------- plan: out = a * exp2((x-lse)*10log2e) * b * n ----------
__global__ __launch_bounds__(256) void k_plan(
    const float* __restrict__ x, const float* __restrict__ lsev,
    float* __restrict__ out, const float* __restrict__ avec,
    const float* __restrict__ bvec) {
  const int wid = threadIdx.x >> 6, lane = threadIdx.x & 63;
  const int row = blockIdx.x * 4 + wid;
  const int batch = row >> 12;
  const float lse = lsev[row];
  const float sc = avec[row] * 4096.0f;
  const float4* xp = (const float4*)(x + ((size_t)row << 10));
  const float4* bp = (const float4*)(bvec + batch * BSTR);
  float4* op = (float4*)(out + ((size_t)row << 10));
#pragma unroll
  for (int s = 0; s < 4; ++s) {
    const float4 v = xp[(lane << 2) + s];
    const float4 b = bp[(lane << 2) + s];
    float4 o;
    o.x = exp2f((v.x - lse) * TLOG2E) * sc * b.x;
    o.y = exp2f((v.y - lse) * TLOG2E) * sc * b.y;
    o.z = exp2f((v.z - lse) * TLOG2E) * sc * b.z;
    o.w = exp2f((v.w - lse) * TLOG2E) * sc * b.w;
    op[(lane << 2) + s] = o;
  }
}

extern "C" void kernel_launch(void* const* d_in, const int* in_sizes, int n_in,
                              void* d_out, int out_size, void* d_ws, size_t ws_size,
                              hipStream_t stream) {
  const float* logits = (const float*)d_in[0];
  unsigned short* Qb = (unsigned short*)d_out;   // bf16 Q in first half of d_out
  float* ws = (float*)d_ws;
  float* bnew     = ws;                          // 16*1028
  float* avec     = bnew + Bn * BSTR;            // 65536
  float* lsev     = avec + ROWS;                 // 65536
  float* part     = lsev + ROWS;                 // 1024*1024
  float* sumaPart = part + (size_t)NBLK * Kc;    // 1024
  float* e2acc    = sumaPart + NBLK;             // NITER+1
  int*   cnt2     = (int*)(e2acc + NITER + 1);   // NITER+1
  int*   flag     = cnt2 + NITER + 1;            // 1
  int*   ready    = flag + 1;                    // 1

  k_init<<<64, 256, 0, stream>>>(bnew, e2acc, cnt2, flag, ready);
  k_iter<true><<<NBLK, 256, 0, stream>>>(logits, Qb, lsev, bnew, avec, part,
                                         sumaPart, e2acc, cnt2, flag, ready, 0);
  for (int it = 1; it < NITER; ++it)
    k_iter<false><<<NBLK, 256, 0, stream>>>(logits, Qb, lsev, bnew, avec, part,
                                            sumaPart, e2acc, cnt2, flag, ready, it);
  k_fin_tail<<<64, 256, 0, stream>>>(part, sumaPart, bnew, e2acc, cnt2, flag, ready);
  k_plan<<<ROWS / 4, 256, 0, stream>>>(logits, lsev, (float*)d_out, avec, bnew);
}

// Round 7
// 3244.990 us; speedup vs baseline: 2.2248x; 1.2784x over previous
//
#include <hip/hip_runtime.h>
#include <math.h>

// Semi-relaxed Sinkhorn-Knopp, MI355X. B=16, n=4096, k=1024, K=1025.
// R7: ONE launch per iteration, ZERO sync/atomics. 512 blocks x 512 threads;
// each block owns 128 rows. At launch head, EVERY block redundantly reduces
// its batch's 32x1024 column partials (written by the previous launch; plain
// loads — kernel boundary gives coherence) into b_t in LDS, then streams its
// Q slice (bf16, d_out) computing a-updates and new column partials. part/suma
// ping-pong buffers kill the same-launch WAR hazard. e2/err: only each batch's
// sub0 block computes it; the stop test uses err from one launch back (lag-1,
// semantically negligible: err never approaches 1e-6 in 100 iters; a stopped
// launch writes nothing so e2 stays 0 and the stop cascades). Plan materializes
// the final b the same way and recomputes fp32 Q from logits + cached lse.

namespace {
constexpr int   Bn      = 16;
constexpr int   Kc      = 1024;    // k
constexpr int   KK      = 1025;    // K = k+1 (dustbin)
constexpr int   BSTR    = 1028;    // padded b stride
constexpr int   ROWS    = 65536;   // B*n
constexpr int   NBLK    = 512;     // blocks; 32 per batch
constexpr int   TPB     = 512;     // threads; 8 waves
constexpr int   SUBS    = 32;      // blocks per batch
constexpr int   RPB     = 128;     // rows per block
constexpr float PA      = 1.0f / 4096.0f;
constexpr float PB_LOW  = (float)(0.5 / 1024.0);
constexpr float PB_DUST = 0.5f;
constexpr float FI_F    = (float)(1.0 / 1.1); // GAMMA/(GAMMA+EPS)
constexpr float STOP    = 1e-6f;
constexpr int   NITER   = 100;
constexpr float LOG2E   = 1.44269504088896340736f;
constexpr float ILOG2E  = 0.69314718055994530942f;
constexpr float TLOG2E  = 14.4269504088896340736f;  // 10*log2(e)
constexpr float B0      = (float)(1.0 / 1025.0);
} // namespace

typedef __attribute__((ext_vector_type(8))) unsigned short ushort8;

__device__ __forceinline__ float wredsum(float v) {
#pragma unroll
  for (int m = 32; m >= 1; m >>= 1) v += __shfl_xor(v, m, 64);
  return v;
}
__device__ __forceinline__ float wredmax(float v) {
#pragma unroll
  for (int m = 32; m >= 1; m >>= 1) v = fmaxf(v, __shfl_xor(v, m, 64));
  return v;
}
__device__ __forceinline__ unsigned short f2bf(float x) {
  unsigned int u = __float_as_uint(x);
  return (unsigned short)((u + 0x7FFFu + ((u >> 16) & 1u)) >> 16);  // RNE
}
__device__ __forceinline__ float bf2f(unsigned short h) {
  return __uint_as_float(((unsigned int)h) << 16);
}

// ---------------- init ----------------
__global__ void k_init(float* __restrict__ bstore, float* __restrict__ e2vec) {
  int tid = blockIdx.x * blockDim.x + threadIdx.x;
  int stride = gridDim.x * blockDim.x;
  for (int i = tid; i < Bn * BSTR; i += stride) {
    int j = i % BSTR;
    bstore[i] = (j < KK) ? B0 : 0.0f;
  }
  for (int i = tid; i < NITER * Bn; i += stride)
    e2vec[i] = (i == 0) ? 1.0f : 0.0f;   // err_0 = 1.0, like the reference
}

// MODE: 0 = first iter (prep fused, b = const), 1 = mid iter, 2 = plan
template <int MODE>
__global__ __launch_bounds__(512, 4) void k_step(
    const float* __restrict__ x, unsigned short* __restrict__ Qb,
    float* __restrict__ lsev, float* __restrict__ avec,
    float* __restrict__ bstore,
    const float* __restrict__ partIn, float* __restrict__ partOut,
    const float* __restrict__ sumaIn, float* __restrict__ sumaOut,
    float* __restrict__ e2vec, float* __restrict__ out, const int t) {
  __shared__ float bls[1026];
  __shared__ float cpart[8][1024];
  __shared__ float sred[8];
  __shared__ int sstop;
  const int tid = threadIdx.x, wave = tid >> 6, lane = tid & 63;
  const int blk = blockIdx.x, b = blk >> 5, sub = blk & 31;
  const int j2 = tid << 1;

  if constexpr (MODE != 0) {
    // ---- gate on err from one launch back (cross-batch, fully coherent) ----
    if (tid == 0) {
      float s = 0.0f;
#pragma unroll
      for (int j = 0; j < Bn; ++j) s += e2vec[(t - 1) * Bn + j];
      sstop = (!(sqrtf(s) > STOP)) ? 1 : 0;   // NaN also stops, like jnp
    }
    __syncthreads();
    if constexpr (MODE == 1) { if (sstop) return; }

    if (MODE == 2 && sstop) {
      // stopped earlier: final b is in bstore
      bls[j2]     = bstore[b * BSTR + j2];
      bls[j2 + 1] = bstore[b * BSTR + j2 + 1];
      if (tid == 0) bls[1024] = bstore[b * BSTR + 1024];
    } else {
      // ---- redundant fin: reduce this batch's 32x1024 partials -> b_t ----
      const float* pb = partIn + ((size_t)b << 15);  // b*32*1024
      float s0 = 0.0f, s1 = 0.0f;
#pragma unroll 8
      for (int sb = 0; sb < SUBS; ++sb) {
        const float2 v = *(const float2*)(pb + (sb << 10) + j2);
        s0 += v.x; s1 += v.y;
      }
      const float bn0 = exp2f(FI_F * log2f(PB_LOW / s0));
      const float bn1 = exp2f(FI_F * log2f(PB_LOW / s1));
      bls[j2] = bn0; bls[j2 + 1] = bn1;
      if (wave == 0) {                       // dustbin
        float sa = (lane < SUBS) ? sumaIn[(b << 5) + lane] : 0.0f;
        sa = wredsum(sa);
        if (lane == 0) bls[1024] = PB_DUST / sa;
      }
      if constexpr (MODE == 1) {
        if (sub == 0) {                      // only sub0 computes e2 + bstore
          const float bo0 = bstore[b * BSTR + j2];
          const float bo1 = bstore[b * BSTR + j2 + 1];
          float e2 = (bn0 - bo0) * (bn0 - bo0) + (bn1 - bo1) * (bn1 - bo1);
          const float ew = wredsum(e2);
          if (lane == 0) sred[wave] = ew;
          __syncthreads();                   // also orders bls[1024]
          if (tid == 0) {
            float tt = 0.0f;
#pragma unroll
            for (int w = 0; w < 8; ++w) tt += sred[w];
            const float bd = bls[1024], bod = bstore[b * BSTR + 1024];
            tt += (bd - bod) * (bd - bod);
            e2vec[t * Bn + b] = tt;
            bstore[b * BSTR + 1024] = bd;
          }
          bstore[b * BSTR + j2]     = bn0;
          bstore[b * BSTR + j2 + 1] = bn1;
        }
      }
    }
    __syncthreads();   // bls complete for all waves
  }

  if constexpr (MODE == 2) {
    // ---------------- plan: out = a * exp2((x-lse)*10log2e) * b * n --------
    float4 bb[4];
#pragma unroll
    for (int s = 0; s < 4; ++s) bb[s] = *(const float4*)&bls[(lane << 4) + (s << 2)];
    const int rowBase = blk * RPB + wave * 16;
    for (int r = 0; r < 16; ++r) {
      const int row = rowBase + r;
      const float lse = lsev[row];
      const float sc = avec[row] * 4096.0f;
      const float4* xp = (const float4*)(x + ((size_t)row << 10));
      float4* op = (float4*)(out + ((size_t)row << 10));
#pragma unroll
      for (int s = 0; s < 4; ++s) {
        const float4 v = xp[(lane << 2) + s];
        float4 o;
        o.x = exp2f((v.x - lse) * TLOG2E) * sc * bb[s].x;
        o.y = exp2f((v.y - lse) * TLOG2E) * sc * bb[s].y;
        o.z = exp2f((v.z - lse) * TLOG2E) * sc * bb[s].z;
        o.w = exp2f((v.w - lse) * TLOG2E) * sc * bb[s].w;
        op[(lane << 2) + s] = o;
      }
    }
    return;
  }

  // ---------------- Q-pass (MODE 0/1) ----------------
  float4 bb[4];
  float bdust;
  if constexpr (MODE == 0) {
    const float4 c = make_float4(B0, B0, B0, B0);
#pragma unroll
    for (int s = 0; s < 4; ++s) bb[s] = c;
    bdust = B0;
  } else {
#pragma unroll
    for (int s = 0; s < 4; ++s) bb[s] = *(const float4*)&bls[(lane << 4) + (s << 2)];
    bdust = bls[1024];
  }

  float acc[16];
#pragma unroll
  for (int e = 0; e < 16; ++e) acc[e] = 0.0f;
  float sal = 0.0f;

  const int rowBase = blk * RPB + wave * 16;
#pragma unroll 4
  for (int r = 0; r < 16; ++r) {
    float q[16];
    if constexpr (MODE == 0) {
      const float4* xp = (const float4*)(x + ((size_t)(rowBase + r) << 10));
      float4 v[4];
#pragma unroll
      for (int s = 0; s < 4; ++s) v[s] = xp[(lane << 2) + s];
      float m = -1e30f;
#pragma unroll
      for (int s = 0; s < 4; ++s)
        m = fmaxf(m, fmaxf(fmaxf(v[s].x, v[s].y), fmaxf(v[s].z, v[s].w)));
      m = wredmax(m);
      float su = 0.0f;
#pragma unroll
      for (int s = 0; s < 4; ++s)
        su += exp2f((v[s].x - m) * LOG2E) + exp2f((v[s].y - m) * LOG2E) +
              exp2f((v[s].z - m) * LOG2E) + exp2f((v[s].w - m) * LOG2E);
      su = wredsum(su);
      const float lse = m + log2f(su) * ILOG2E;
      if (lane == 0) lsev[rowBase + r] = lse;
      ushort8 qa, qb2;
#pragma unroll
      for (int s = 0; s < 4; ++s) {
        const unsigned short u0 = f2bf(exp2f((v[s].x - lse) * TLOG2E));
        const unsigned short u1 = f2bf(exp2f((v[s].y - lse) * TLOG2E));
        const unsigned short u2 = f2bf(exp2f((v[s].z - lse) * TLOG2E));
        const unsigned short u3 = f2bf(exp2f((v[s].w - lse) * TLOG2E));
        if (s < 2) { qa[s*4+0]=u0; qa[s*4+1]=u1; qa[s*4+2]=u2; qa[s*4+3]=u3; }
        else { qb2[(s-2)*4+0]=u0; qb2[(s-2)*4+1]=u1; qb2[(s-2)*4+2]=u2; qb2[(s-2)*4+3]=u3; }
        q[s*4+0]=bf2f(u0); q[s*4+1]=bf2f(u1); q[s*4+2]=bf2f(u2); q[s*4+3]=bf2f(u3);
      }
      ushort8* qp = (ushort8*)(Qb + ((size_t)(rowBase + r) << 10));
      qp[lane * 2] = qa; qp[lane * 2 + 1] = qb2;
    } else {
      const ushort8* qp = (const ushort8*)(Qb + ((size_t)(rowBase + r) << 10));
      const ushort8 qa = qp[lane * 2], qb2 = qp[lane * 2 + 1];
#pragma unroll
      for (int e = 0; e < 8; ++e) { q[e] = bf2f(qa[e]); q[8 + e] = bf2f(qb2[e]); }
    }

    float p = 0.0f;
#pragma unroll
    for (int s = 0; s < 4; ++s)
      p += q[s * 4 + 0] * bb[s].x + q[s * 4 + 1] * bb[s].y +
           q[s * 4 + 2] * bb[s].z + q[s * 4 + 3] * bb[s].w;

    const float inner = wredsum(p) + bdust;       // dustbin Q == 1
    const float a = PA / inner;                   // broadcast to all lanes
    if (lane == 0) { avec[rowBase + r] = a; sal += a; }
#pragma unroll
    for (int e = 0; e < 16; ++e) acc[e] += q[e] * a;
  }
  if (lane == 0) sred[wave] = sal;

  float4* cp = (float4*)&cpart[wave][lane << 4];
#pragma unroll
  for (int s = 0; s < 4; ++s)
    cp[s] = make_float4(acc[s * 4 + 0], acc[s * 4 + 1], acc[s * 4 + 2], acc[s * 4 + 3]);
  __syncthreads();

  float o0 = 0.0f, o1 = 0.0f;
#pragma unroll
  for (int w = 0; w < 8; ++w) { o0 += cpart[w][j2]; o1 += cpart[w][j2 + 1]; }
  *(float2*)(partOut + ((size_t)b << 15) + (sub << 10) + j2) = make_float2(o0, o1);
  if (tid == 0) {
    float ss = 0.0f;
#pragma unroll
    for (int w = 0; w < 8; ++w) ss += sred[w];
    sumaOut[(b << 5) + sub] = ss;
  }
}

extern "C" void kernel_launch(void* const* d_in, const int* in_sizes, int n_in,
                              void* d_out, int out_size, void* d_ws, size_t ws_size,
                              hipStream_t stream) {
  const float* logits = (const float*)d_in[0];
  unsigned short* Qb = (unsigned short*)d_out;   // bf16 Q in first half of d_out
  float* ws = (float*)d_ws;
  float* bstore = ws;                            // 16*1028
  float* avec   = bstore + Bn * BSTR;            // 65536
  float* lsev   = avec + ROWS;                   // 65536
  float* partA  = lsev + ROWS;                   // 16*32*1024
  float* partB  = partA + (size_t)Bn * SUBS * Kc;
  float* sumaA  = partB + (size_t)Bn * SUBS * Kc; // 512
  float* sumaB  = sumaA + NBLK;                   // 512
  float* e2vec  = sumaB + NBLK;                   // 100*16

  k_init<<<16, 256, 0, stream>>>(bstore, e2vec);
  k_step<0><<<NBLK, TPB, 0, stream>>>(logits, Qb, lsev, avec, bstore,
                                      partA, partA, sumaA, sumaA, e2vec, nullptr, 0);
  for (int t = 1; t < NITER; ++t) {
    const bool odd = (t & 1) != 0;
    k_step<1><<<NBLK, TPB, 0, stream>>>(logits, Qb, lsev, avec, bstore,
                                        odd ? partA : partB, odd ? partB : partA,
                                        odd ? sumaA : sumaB, odd ? sumaB : sumaA,
                                        e2vec, nullptr, t);
  }
  // NITER-1 = 99 is odd -> last iteration wrote partB/sumaB
  k_step<2><<<NBLK, TPB, 0, stream>>>(logits, Qb, lsev, avec, bstore,
                                      partB, partA, sumaB, sumaA, e2vec,
                                      (float*)d_out, NITER);
}